// Round 10
// baseline (286.589 us; speedup 1.0000x reference)
//
#include <hip/hip_runtime.h>
#include <hip/hip_bf16.h>

#define TT 2048
#define CC 2048
#define HH 16
#define HS 128
#define BB 2
#define MM (BB*TT)   // 4096

typedef __attribute__((ext_vector_type(8))) short bf16x8;
typedef __attribute__((ext_vector_type(4))) short bf16x4;
typedef __attribute__((ext_vector_type(4))) float f32x4;
typedef __attribute__((ext_vector_type(16))) float f32x16;

__device__ __forceinline__ short f2bf(float x) {
    unsigned u = __float_as_uint(x);
    unsigned r = (u + 0x7FFFu + ((u >> 16) & 1u)) >> 16;
    return (short)r;
}

// direct global -> LDS async copy, 16B per lane (dest wave-uniform base + lane*16)
__device__ __forceinline__ void gl_lds16(const void* g, void* l) {
    __builtin_amdgcn_global_load_lds(
        (const __attribute__((address_space(1))) unsigned int*)g,
        (__attribute__((address_space(3))) unsigned int*)l,
        16, 0, 0);
}

__device__ __forceinline__ void rbar() {
    asm volatile("" ::: "memory");
    __builtin_amdgcn_s_barrier();
    asm volatile("" ::: "memory");
}
#define VM4  asm volatile("s_waitcnt vmcnt(4)" ::: "memory")
#define VM0  asm volatile("s_waitcnt vmcnt(0)" ::: "memory")

// ---------------- fp32 -> bf16 convert (idx) ----------------
__global__ void cvt_bf16_kernel(const float* __restrict__ x, short* __restrict__ y, int n) {
    int stride = gridDim.x * blockDim.x;
    for (int i = blockIdx.x * blockDim.x + threadIdx.x; i < n/4; i += stride) {
        float4 v = reinterpret_cast<const float4*>(x)[i];
        bf16x4 s;
        s[0] = f2bf(v.x); s[1] = f2bf(v.y); s[2] = f2bf(v.z); s[3] = f2bf(v.w);
        reinterpret_cast<bf16x4*>(y)[i] = s;
    }
}

// ---------------- W [k][n] fp32  ->  Wt [n][k] bf16 ----------------
__global__ void wt_kernel(const float* __restrict__ w0, const float* __restrict__ w1,
                          const float* __restrict__ w2, const float* __restrict__ w3,
                          short* __restrict__ o0, short* __restrict__ o1,
                          short* __restrict__ o2, short* __restrict__ o3)
{
    const float* W; short* Wt;
    switch (blockIdx.z) {
        case 0:  W = w0; Wt = o0; break;
        case 1:  W = w1; Wt = o1; break;
        case 2:  W = w2; Wt = o2; break;
        default: W = w3; Wt = o3; break;
    }
    __shared__ float tile[32][33];
    int tx = threadIdx.x, ty = threadIdx.y;           // block (32,8)
    int k0 = blockIdx.x * 32, n0 = blockIdx.y * 32;
    #pragma unroll
    for (int i = 0; i < 4; ++i)
        tile[ty + i*8][tx] = W[(size_t)(k0 + ty + i*8) * CC + n0 + tx];
    __syncthreads();
    #pragma unroll
    for (int i = 0; i < 4; ++i)
        Wt[(size_t)(n0 + ty + i*8) * CC + k0 + tx] = f2bf(tile[tx][ty + i*8]);
}

// ---------------- QKV GEMM: 256x256 tile, BK=64, 8 waves (2M x 4N), 8-phase schedule ----------------
// C[4096][6144] = Xbf * Wcat^T; epilogue routes n-tile -> Q(scaled)/K/Vt.
// Per phase: vmcnt(4); ds_read subtile; stage 1 half-tile (2 gl_lds); bar; [MFMA x16 setprio]; bar.
// Stage schedule (derived, all stage->read distances >= 6 phases):
//   ph1: buf1.A1(2i+1)  ph2: buf0.A0(2i+2)  ph3: buf0.B0(2i+2)  ph4: buf0.B1(2i+2)
//   ph5: buf0.A1(2i+2)  ph6: buf1.A0(2i+3)  ph7: buf1.B0(2i+3)  ph8: buf1.B1(2i+3)
__launch_bounds__(512, 1)
__global__ void gemm_qkv8_kernel(const short* __restrict__ A, const short* __restrict__ Wcat,
                                 const float* __restrict__ bq, const float* __restrict__ bk,
                                 const float* __restrict__ bv,
                                 short* __restrict__ Qd, short* __restrict__ Kd,
                                 short* __restrict__ Vtd, float qscale)
{
    __shared__ __align__(16) short As[2][256*64];   // 2 x 32KB
    __shared__ __align__(16) short Bs[2][256*64];   // 2 x 32KB  (total 128KB)

    const int tid = threadIdx.x;
    const int lane = tid & 63;
    const int g = lane >> 4, fr = lane & 15;
    const int wid = tid >> 6;
    const int wm = wid >> 2, wn = wid & 3;          // 2 M-waves x 4 N-waves

    const int bid = blockIdx.x;                     // 0..383, m fastest
    const int m0 = (bid & 15) * 256;                // 16 m-tiles
    const int n0 = (bid >> 4) * 256;                // 24 n-tiles (N=6144)

    const char* Ab = (const char*)A;
    const char* Bb = (const char*)(Wcat + (size_t)n0 * CC);

    // A-half h: rows {h*64..+64} U {128+h*64..+64}  (the rows quadrant mr=h reads, both wm groups)
    auto stageA = [&](int h, int tt, int b) {
        if (tt >= CC/64) return;
        char* dst = (char*)As[b];
        #pragma unroll
        for (int i = 0; i < 2; ++i) {
            int c  = i*512 + tid;
            int rh = c >> 3;
            int row = (rh & 63) + h*64 + (rh >> 6)*128;
            int kb  = (c & 7) * 16;
            gl_lds16(Ab + ((size_t)(m0 + row)*CC + tt*64)*2 + (kb ^ ((row & 7) << 4)),
                     dst + row*128 + kb);
        }
    };
    // B-half nc: rows {wn*64+nc*32..+32} for all 4 wn groups
    auto stageB = [&](int nc, int tt, int b) {
        if (tt >= CC/64) return;
        char* dst = (char*)Bs[b];
        #pragma unroll
        for (int i = 0; i < 2; ++i) {
            int c  = i*512 + tid;
            int rb = c >> 3;
            int row = (rb & 31) + nc*32 + (rb >> 5)*64;
            int kb  = (c & 7) * 16;
            gl_lds16(Bb + ((size_t)row*CC + tt*64)*2 + (kb ^ ((row & 7) << 4)),
                     dst + row*128 + kb);
        }
    };

    f32x4 acc[2][2][4][2];
    #pragma unroll
    for (int mr = 0; mr < 2; ++mr)
        #pragma unroll
        for (int nc = 0; nc < 2; ++nc)
            #pragma unroll
            for (int m = 0; m < 4; ++m)
                #pragma unroll
                for (int n = 0; n < 2; ++n)
                    acc[mr][nc][m][n] = (f32x4){0.f,0.f,0.f,0.f};

    bf16x8 a[4][2], b0[2][2], b1[2][2];
    const char* A0l = (const char*)As[0];
    const char* A1l = (const char*)As[1];
    const char* B0l = (const char*)Bs[0];
    const char* B1l = (const char*)Bs[1];

#define QLDA(AL, MR) { \
    _Pragma("unroll") for (int m_ = 0; m_ < 4; ++m_) { \
        _Pragma("unroll") for (int kk_ = 0; kk_ < 2; ++kk_) { \
            int row_ = wm*128 + (MR)*64 + m_*16 + fr; \
            a[m_][kk_] = *(const bf16x8*)((AL) + row_*128 + ((kk_*64 + g*16) ^ ((row_ & 7) << 4))); \
        } } }
#define QLDB(BL, NC, BB_) { \
    _Pragma("unroll") for (int n_ = 0; n_ < 2; ++n_) { \
        _Pragma("unroll") for (int kk_ = 0; kk_ < 2; ++kk_) { \
            int row_ = wn*64 + (NC)*32 + n_*16 + fr; \
            BB_[n_][kk_] = *(const bf16x8*)((BL) + row_*128 + ((kk_*64 + g*16) ^ ((row_ & 7) << 4))); \
        } } }
#define QMM(MR, NC, BB_) { \
    __builtin_amdgcn_s_setprio(1); \
    _Pragma("unroll") for (int m_ = 0; m_ < 4; ++m_) { \
        _Pragma("unroll") for (int n_ = 0; n_ < 2; ++n_) { \
            _Pragma("unroll") for (int kk_ = 0; kk_ < 2; ++kk_) { \
                acc[MR][NC][m_][n_] = __builtin_amdgcn_mfma_f32_16x16x32_bf16( \
                    a[m_][kk_], BB_[n_][kk_], acc[MR][NC][m_][n_], 0, 0, 0); \
        } } } \
    __builtin_amdgcn_s_setprio(0); }

    // prologue: t0 {A0,B0,B1,A1}, t1 {A0,B0,B1}; t1.A1 staged at i0.ph1
    stageA(0, 0, 0); stageB(0, 0, 0); stageB(1, 0, 0); stageA(1, 0, 0);
    stageA(0, 1, 1); stageB(0, 1, 1); stageB(1, 1, 1);
    VM0;
    rbar();

    const int NI = CC/128;              // 16 iterations, 2 K-tiles each
    #pragma unroll 1
    for (int i = 0; i < NI; ++i) {
        const int t1 = 2*i + 1, t2 = 2*i + 2, t3 = 2*i + 3;
        // ---- K-tile 2i from buf0 ----
        // ph1 (mr0,nc0): reads A0,B0
        VM4; QLDA(A0l, 0); QLDB(B0l, 0, b0); stageA(1, t1, 1);
        rbar(); QMM(0, 0, b0); rbar();
        // ph2 (mr0,nc1): reads B1 (a reused)
        VM4; QLDB(B0l, 1, b1); stageA(0, t2, 0);
        rbar(); QMM(0, 1, b1); rbar();
        // ph3 (mr1,nc0): reads A1 (b0 reused)
        VM4; QLDA(A0l, 1); stageB(0, t2, 0);
        rbar(); QMM(1, 0, b0); rbar();
        // ph4 (mr1,nc1): pure MFMA (a, b1 reused)
        VM4; stageB(1, t2, 0);
        rbar(); QMM(1, 1, b1); rbar();
        // ---- K-tile 2i+1 from buf1 ----
        // ph5
        VM4; QLDA(A1l, 0); QLDB(B1l, 0, b0); stageA(1, t2, 0);
        rbar(); QMM(0, 0, b0); rbar();
        // ph6
        VM4; QLDB(B1l, 1, b1); stageA(0, t3, 1);
        rbar(); QMM(0, 1, b1); rbar();
        // ph7
        VM4; QLDA(A1l, 1); stageB(0, t3, 1);
        rbar(); QMM(1, 0, b0); rbar();
        // ph8
        VM4; stageB(1, t3, 1);
        rbar(); QMM(1, 1, b1); rbar();
    }
#undef QLDA
#undef QLDB
#undef QMM

    // ---- epilogue: route n-tile (block-uniform section) -> Q / K / Vt ----
    const int sec = n0 >> 11;                      // 0..2 (n0 multiple of 256, sections 2048-aligned)
    const float scl = (sec == 0) ? qscale : 1.0f;
    const float* bp = (sec == 0) ? bq : ((sec == 1) ? bk : bv);
    #pragma unroll
    for (int mr = 0; mr < 2; ++mr)
        #pragma unroll
        for (int nc = 0; nc < 2; ++nc)
            #pragma unroll
            for (int n = 0; n < 2; ++n) {
                int nn = (n0 & 2047) + wn*64 + nc*32 + n*16 + fr;
                float bval = bp[nn];
                int h = nn >> 7, d = nn & (HS-1);
                #pragma unroll
                for (int m = 0; m < 4; ++m)
                    #pragma unroll
                    for (int r = 0; r < 4; ++r) {
                        int mg = m0 + wm*128 + mr*64 + m*16 + g*4 + r;
                        int bb2 = mg >> 11, tq = mg & (TT-1);
                        short ov = f2bf((acc[mr][nc][m][n][r] + bval) * scl);
                        if (sec == 0)      Qd [((size_t)(bb2*HH + h)*TT + tq)*HS + d] = ov;
                        else if (sec == 1) Kd [((size_t)(bb2*HH + h)*TT + tq)*HS + d] = ov;
                        else               Vtd[((size_t)(bb2*HH + h)*HS + d)*TT + tq] = ov;
                    }
            }
}

// ---------------- out-proj GEMM (proven 128^2 structure), fp32 out ----------------
__launch_bounds__(256)
__global__ void gemm_out_kernel(const short* __restrict__ A, const short* __restrict__ Bt,
                                const float* __restrict__ bias, float* __restrict__ dst)
{
    __shared__ __align__(16) short As[128*64];
    __shared__ __align__(16) short Bs[128*64];
    const int tid = threadIdx.x;
    const int lane = tid & 63;
    const int g = lane >> 4, fr = lane & 15;
    const int wid = tid >> 6;
    const int wr = wid >> 1, wc = wid & 1;

    const int bid = blockIdx.x;                   // 0..511
    const int m0 = (bid & 31) * 128;              // 32 m-tiles (fastest)
    const int n0 = (bid >> 5) * 128;              // 16 n-tiles

    f32x4 acc[4][4];
    #pragma unroll
    for (int i = 0; i < 4; ++i)
        #pragma unroll
        for (int j = 0; j < 4; ++j) acc[i][j] = (f32x4){0.f,0.f,0.f,0.f};

    for (int k0 = 0; k0 < CC; k0 += 64) {
        __syncthreads();
        #pragma unroll
        for (int i = 0; i < 4; ++i) {
            int c = i*256 + tid;
            int row = c >> 3;
            int kbl = ((c & 7) * 16) ^ ((row & 7) << 4);
            gl_lds16(reinterpret_cast<const char*>(A) + ((size_t)(m0+row)*CC + k0)*2 + kbl,
                     reinterpret_cast<char*>(As) + c*16);
        }
        #pragma unroll
        for (int i = 0; i < 4; ++i) {
            int c = i*256 + tid;
            int row = c >> 3;
            int kbl = ((c & 7) * 16) ^ ((row & 7) << 4);
            gl_lds16(reinterpret_cast<const char*>(Bt) + ((size_t)(n0+row)*CC + k0)*2 + kbl,
                     reinterpret_cast<char*>(Bs) + c*16);
        }
        __syncthreads();
        #pragma unroll
        for (int cch = 0; cch < 2; ++cch) {
            bf16x8 a[4], b[4];
            #pragma unroll
            for (int i = 0; i < 4; ++i) {
                int row = wr*64 + i*16 + fr;
                int kph = (cch*64 + g*16) ^ ((row & 7) << 4);
                a[i] = *reinterpret_cast<const bf16x8*>(
                    reinterpret_cast<const char*>(As) + row*128 + kph);
            }
            #pragma unroll
            for (int j = 0; j < 4; ++j) {
                int row = wc*64 + j*16 + fr;
                int kph = (cch*64 + g*16) ^ ((row & 7) << 4);
                b[j] = *reinterpret_cast<const bf16x8*>(
                    reinterpret_cast<const char*>(Bs) + row*128 + kph);
            }
            #pragma unroll
            for (int i = 0; i < 4; ++i)
                #pragma unroll
                for (int j = 0; j < 4; ++j)
                    acc[i][j] = __builtin_amdgcn_mfma_f32_16x16x32_bf16(a[i], b[j], acc[i][j], 0, 0, 0);
        }
    }

    #pragma unroll
    for (int j = 0; j < 4; ++j) {
        int n = n0 + wc*64 + j*16 + fr;
        float bval = bias[n];
        #pragma unroll
        for (int i = 0; i < 4; ++i)
            #pragma unroll
            for (int r = 0; r < 4; ++r) {
                int m = m0 + wr*64 + i*16 + g*4 + r;
                dst[(size_t)m*CC + n] = acc[i][j][r] + bval;
            }
    }
}

// ---------------- causal flash attention v5 + setprio (unchanged from round 9) ----------------
__launch_bounds__(256, 2)
__global__ void attn_kernel(const short* __restrict__ Q, const short* __restrict__ K,
                            const short* __restrict__ Vt, short* __restrict__ O)
{
    __shared__ __align__(16) short Ks[2][64*128];   // 2 x 16KB
    __shared__ __align__(16) short Vs[2][128*64];   // 2 x 16KB

    const int tid = threadIdx.x;
    const int lane = tid & 63;
    const int wid = tid >> 6;
    const int l5 = lane >> 5;
    const int q31 = lane & 31;
    const bool hif = (l5 != 0);

    const int dd = blockIdx.x;              // 0..511
    const int g8 = dd & 7;
    const int s  = (dd >> 3) & 31;
    const int half = dd >> 8;
    const int bh = g8*4 + (s >> 3);
    const int u  = s & 7;
    const int qb = half ? u : (15 - u);
    const int q0 = qb * 128;
    const int wq0 = q0 + wid*32;

    const short* Qh = Q + (size_t)bh * TT * HS;
    const char*  Kg = (const char*)(K  + (size_t)bh * TT * HS);
    const char*  Vg = (const char*)(Vt + (size_t)bh * HS * TT);

    bf16x8 qf[8];
    #pragma unroll
    for (int dk = 0; dk < 8; ++dk)
        qf[dk] = *reinterpret_cast<const bf16x8*>(
            Qh + (size_t)(wq0 + q31)*HS + dk*16 + l5*8);

    f32x16 o[4];
    #pragma unroll
    for (int c = 0; c < 4; ++c)
        #pragma unroll
        for (int r = 0; r < 16; ++r) o[c][r] = 0.f;
    float mrun = -1e30f, lrun = 0.f;

    auto stage = [&](int kv0, int p) {
        char* Kd = reinterpret_cast<char*>(Ks[p]);
        char* Vd = reinterpret_cast<char*>(Vs[p]);
        #pragma unroll
        for (int i = 0; i < 4; ++i) {
            int c = i*256 + tid;
            int row = c >> 4;
            int lg  = ((c & 15) * 16) ^ ((row & 7) << 4);
            gl_lds16(Kg + (size_t)(kv0 + row)*256 + lg, Kd + c*16);
        }
        #pragma unroll
        for (int i = 0; i < 4; ++i) {
            int c = i*256 + tid;
            int row = c >> 3;
            int lg  = ((c & 7) * 16) ^ ((row & 7) << 4);
            gl_lds16(Vg + ((size_t)row*TT + kv0)*2 + lg, Vd + c*16);
        }
    };

    const int nst = q0/64 + 2;
    stage(0, 0);

    for (int t = 0; t < nst; ++t) {
        const int kv0 = t * 64;
        __syncthreads();
        if (t + 1 < nst) stage(kv0 + 64, (t+1) & 1);

        if (kv0 > wq0 + 31) continue;

        const char* Kl = reinterpret_cast<const char*>(Ks[t & 1]);
        const char* Vl = reinterpret_cast<const char*>(Vs[t & 1]);

        f32x16 st[2];
        #pragma unroll
        for (int t2 = 0; t2 < 2; ++t2)
            #pragma unroll
            for (int r = 0; r < 16; ++r) st[t2][r] = 0.f;
        __builtin_amdgcn_s_setprio(1);
        #pragma unroll
        for (int t2 = 0; t2 < 2; ++t2) {
            int krow = t2*32 + q31;
            int rsw = (krow & 7) << 4;
            #pragma unroll
            for (int dk = 0; dk < 8; ++dk) {
                bf16x8 kf = *reinterpret_cast<const bf16x8*>(
                    Kl + krow*256 + ((dk*32 + l5*16) ^ rsw));
                st[t2] = __builtin_amdgcn_mfma_f32_32x32x16_bf16(kf, qf[dk], st[t2], 0, 0, 0);
            }
        }
        __builtin_amdgcn_s_setprio(0);
        if (kv0 + 63 > wq0) {
            int qrow = wq0 + q31;
            #pragma unroll
            for (int t2 = 0; t2 < 2; ++t2)
                #pragma unroll
                for (int r = 0; r < 16; ++r) {
                    int kv = kv0 + t2*32 + (r & 3) + ((r >> 2) << 3) + l5*4;
                    if (kv > qrow) st[t2][r] = -1e30f;
                }
        }
        float pm = -1e30f;
        #pragma unroll
        for (int t2 = 0; t2 < 2; ++t2)
            #pragma unroll
            for (int r = 0; r < 16; ++r) pm = fmaxf(pm, st[t2][r]);
        if (__any(pm > mrun + 8.f)) {
            float pmf = fmaxf(pm, __shfl_xor(pm, 32));
            float mn = fmaxf(mrun, pmf);
            float al = __builtin_amdgcn_exp2f(mrun - mn);
            mrun = mn; lrun *= al;
            #pragma unroll
            for (int c = 0; c < 4; ++c)
                #pragma unroll
                for (int r = 0; r < 16; ++r) o[c][r] *= al;
        }
        float ps = 0.f;
        #pragma unroll
        for (int t2 = 0; t2 < 2; ++t2)
            #pragma unroll
            for (int r = 0; r < 16; ++r) {
                float pv = __builtin_amdgcn_exp2f(st[t2][r] - mrun);
                st[t2][r] = pv;
                ps += pv;
            }
        lrun += ps;
        unsigned pw[2][8];
        #pragma unroll
        for (int t2 = 0; t2 < 2; ++t2)
            #pragma unroll
            for (int w = 0; w < 8; ++w)
                asm("v_cvt_pk_bf16_f32 %0, %1, %2"
                    : "=v"(pw[t2][w]) : "v"(st[t2][2*w]), "v"(st[t2][2*w+1]));
        #pragma unroll
        for (int c4 = 0; c4 < 4; ++c4) {
            int t2 = c4 >> 1, b0 = (c4 & 1) * 4;
            unsigned A0 = pw[t2][b0+0], A1 = pw[t2][b0+1];
            unsigned A2 = pw[t2][b0+2], A3 = pw[t2][b0+3];
            unsigned X0 = (unsigned)__shfl_xor((int)A0, 32);
            unsigned X1 = (unsigned)__shfl_xor((int)A1, 32);
            unsigned X2 = (unsigned)__shfl_xor((int)A2, 32);
            unsigned X3 = (unsigned)__shfl_xor((int)A3, 32);
            union { unsigned u[4]; bf16x8 v; } fu;
            fu.u[0] = hif ? X2 : A0;
            fu.u[1] = hif ? X3 : A1;
            fu.u[2] = hif ? A2 : X0;
            fu.u[3] = hif ? A3 : X1;
            __builtin_amdgcn_s_setprio(1);
            #pragma unroll
            for (int c = 0; c < 4; ++c) {
                int vrow = c*32 + q31;
                bf16x8 vf = *reinterpret_cast<const bf16x8*>(
                    Vl + vrow*128 + ((c4*32 + l5*16) ^ ((vrow & 7) << 4)));
                o[c] = __builtin_amdgcn_mfma_f32_32x32x16_bf16(vf, fu.v, o[c], 0, 0, 0);
            }
            __builtin_amdgcn_s_setprio(0);
        }
    }

    lrun += __shfl_xor(lrun, 32);
    float inv = 1.f / lrun;
    int b = bh >> 4, h = bh & 15;
    size_t base = ((size_t)(b*TT + wq0 + q31))*CC + (size_t)h*HS;
    #pragma unroll
    for (int c = 0; c < 4; ++c)
        #pragma unroll
        for (int g2 = 0; g2 < 4; ++g2) {
            bf16x4 v4;
            #pragma unroll
            for (int j = 0; j < 4; ++j) v4[j] = f2bf(o[c][g2*4 + j] * inv);
            *reinterpret_cast<bf16x4*>(O + base + c*32 + g2*8 + l5*4) = v4;
        }
}

extern "C" void kernel_launch(void* const* d_in, const int* in_sizes, int n_in,
                              void* d_out, int out_size, void* d_ws, size_t ws_size,
                              hipStream_t stream)
{
    const float* idx = (const float*)d_in[0];
    const float* Wq  = (const float*)d_in[1];
    const float* bq  = (const float*)d_in[2];
    const float* Wk  = (const float*)d_in[3];
    const float* bk  = (const float*)d_in[4];
    const float* Wv  = (const float*)d_in[5];
    const float* bv  = (const float*)d_in[6];
    const float* Wo  = (const float*)d_in[7];
    const float* bo  = (const float*)d_in[8];
    float* out = (float*)d_out;

    short* Xbf  = (short*)d_ws;
    short* Wcat = Xbf  + (size_t)MM*CC;          // [6144][2048] = Wq^T | Wk^T | Wv^T
    short* Wto  = Wcat + (size_t)3*CC*CC;
    short* Qb   = Wto  + (size_t)CC*CC;
    short* Kb   = Qb   + (size_t)MM*CC;
    short* Vtb  = Kb   + (size_t)MM*CC;
    short* Ob   = Vtb  + (size_t)MM*CC;

    cvt_bf16_kernel<<<1024, 256, 0, stream>>>(idx, Xbf, MM*CC);
    wt_kernel<<<dim3(CC/32, CC/32, 4), dim3(32, 8), 0, stream>>>(
        Wq, Wk, Wv, Wo,
        Wcat, Wcat + (size_t)CC*CC, Wcat + (size_t)2*CC*CC, Wto);

    const float qs = 0.08838834764831845f * 1.4426950408889634f;  // log2(e)/sqrt(128)
    gemm_qkv8_kernel<<<dim3(384), 512, 0, stream>>>(Xbf, Wcat, bq, bk, bv, Qb, Kb, Vtb, qs);

    attn_kernel<<<dim3(512), 256, 0, stream>>>(Qb, Kb, Vtb, Ob);

    gemm_out_kernel<<<dim3(512), 256, 0, stream>>>(Ob, Wto, bo, out);
}

// Round 11
// 285.972 us; speedup vs baseline: 1.0022x; 1.0022x over previous
//
#include <hip/hip_runtime.h>
#include <hip/hip_bf16.h>

#define TT 2048
#define CC 2048
#define HH 16
#define HS 128
#define BB 2
#define MM (BB*TT)   // 4096

typedef __attribute__((ext_vector_type(8))) short bf16x8;
typedef __attribute__((ext_vector_type(4))) short bf16x4;
typedef __attribute__((ext_vector_type(4))) float f32x4;
typedef __attribute__((ext_vector_type(16))) float f32x16;

__device__ __forceinline__ short f2bf(float x) {
    unsigned u = __float_as_uint(x);
    unsigned r = (u + 0x7FFFu + ((u >> 16) & 1u)) >> 16;
    return (short)r;
}

// direct global -> LDS async copy, 16B per lane (dest wave-uniform base + lane*16)
__device__ __forceinline__ void gl_lds16(const void* g, void* l) {
    __builtin_amdgcn_global_load_lds(
        (const __attribute__((address_space(1))) unsigned int*)g,
        (__attribute__((address_space(3))) unsigned int*)l,
        16, 0, 0);
}

__device__ __forceinline__ void rbar() {
    asm volatile("" ::: "memory");
    __builtin_amdgcn_s_barrier();
    asm volatile("" ::: "memory");
}
// Counted wait: min stage->read distance is 6 phases x 2 loads/phase => at any read
// point at most 10 loads are newer than the stage being consumed. vmcnt(10) (NOT 4:
// round-10 bug -- drained the pipeline every phase and exposed HBM latency).
#define VMW  asm volatile("s_waitcnt vmcnt(10)" ::: "memory")
#define VM0  asm volatile("s_waitcnt vmcnt(0)" ::: "memory")

// ---------------- fp32 -> bf16 convert (idx) ----------------
__global__ void cvt_bf16_kernel(const float* __restrict__ x, short* __restrict__ y, int n) {
    int stride = gridDim.x * blockDim.x;
    for (int i = blockIdx.x * blockDim.x + threadIdx.x; i < n/4; i += stride) {
        float4 v = reinterpret_cast<const float4*>(x)[i];
        bf16x4 s;
        s[0] = f2bf(v.x); s[1] = f2bf(v.y); s[2] = f2bf(v.z); s[3] = f2bf(v.w);
        reinterpret_cast<bf16x4*>(y)[i] = s;
    }
}

// ---------------- W [k][n] fp32  ->  Wt [n][k] bf16 ----------------
__global__ void wt_kernel(const float* __restrict__ w0, const float* __restrict__ w1,
                          const float* __restrict__ w2, const float* __restrict__ w3,
                          short* __restrict__ o0, short* __restrict__ o1,
                          short* __restrict__ o2, short* __restrict__ o3)
{
    const float* W; short* Wt;
    switch (blockIdx.z) {
        case 0:  W = w0; Wt = o0; break;
        case 1:  W = w1; Wt = o1; break;
        case 2:  W = w2; Wt = o2; break;
        default: W = w3; Wt = o3; break;
    }
    __shared__ float tile[32][33];
    int tx = threadIdx.x, ty = threadIdx.y;           // block (32,8)
    int k0 = blockIdx.x * 32, n0 = blockIdx.y * 32;
    #pragma unroll
    for (int i = 0; i < 4; ++i)
        tile[ty + i*8][tx] = W[(size_t)(k0 + ty + i*8) * CC + n0 + tx];
    __syncthreads();
    #pragma unroll
    for (int i = 0; i < 4; ++i)
        Wt[(size_t)(n0 + ty + i*8) * CC + k0 + tx] = f2bf(tile[tx][ty + i*8]);
}

// ---------------- QKV GEMM: 256x256 tile, BK=64, 8 waves (2M x 4N), 8-phase schedule ----------------
// C[4096][6144] = Xbf * Wcat^T; epilogue routes n-tile -> Q(scaled)/K/Vt.
// Per phase: vmcnt(10); ds_read subtile; stage 1 half-tile (2 gl_lds); bar; [MFMA x16 setprio]; bar.
// Stage schedule (all stage->read distances >= 6 phases):
//   ph1: buf1.A1(2i+1)  ph2: buf0.A0(2i+2)  ph3: buf0.B0(2i+2)  ph4: buf0.B1(2i+2)
//   ph5: buf0.A1(2i+2)  ph6: buf1.A0(2i+3)  ph7: buf1.B0(2i+3)  ph8: buf1.B1(2i+3)
__launch_bounds__(512, 1)
__global__ void gemm_qkv8_kernel(const short* __restrict__ A, const short* __restrict__ Wcat,
                                 const float* __restrict__ bq, const float* __restrict__ bk,
                                 const float* __restrict__ bv,
                                 short* __restrict__ Qd, short* __restrict__ Kd,
                                 short* __restrict__ Vtd, float qscale)
{
    __shared__ __align__(16) short As[2][256*64];   // 2 x 32KB
    __shared__ __align__(16) short Bs[2][256*64];   // 2 x 32KB  (total 128KB)

    const int tid = threadIdx.x;
    const int lane = tid & 63;
    const int g = lane >> 4, fr = lane & 15;
    const int wid = tid >> 6;
    const int wm = wid >> 2, wn = wid & 3;          // 2 M-waves x 4 N-waves

    const int bid = blockIdx.x;                     // 0..383, m fastest
    const int m0 = (bid & 15) * 256;                // 16 m-tiles
    const int n0 = (bid >> 4) * 256;                // 24 n-tiles (N=6144)

    const char* Ab = (const char*)A;
    const char* Bb = (const char*)(Wcat + (size_t)n0 * CC);

    // A-half h: rows {h*64..+64} U {128+h*64..+64}  (rows quadrant mr=h reads, both wm groups)
    auto stageA = [&](int h, int tt, int b) {
        if (tt >= CC/64) return;
        char* dst = (char*)As[b];
        #pragma unroll
        for (int i = 0; i < 2; ++i) {
            int c  = i*512 + tid;
            int rh = c >> 3;
            int row = (rh & 63) + h*64 + (rh >> 6)*128;
            int kb  = (c & 7) * 16;
            gl_lds16(Ab + ((size_t)(m0 + row)*CC + tt*64)*2 + (kb ^ ((row & 7) << 4)),
                     dst + row*128 + kb);
        }
    };
    // B-half nc: rows {wn*64+nc*32..+32} for all 4 wn groups
    auto stageB = [&](int nc, int tt, int b) {
        if (tt >= CC/64) return;
        char* dst = (char*)Bs[b];
        #pragma unroll
        for (int i = 0; i < 2; ++i) {
            int c  = i*512 + tid;
            int rb = c >> 3;
            int row = (rb & 31) + nc*32 + (rb >> 5)*64;
            int kb  = (c & 7) * 16;
            gl_lds16(Bb + ((size_t)row*CC + tt*64)*2 + (kb ^ ((row & 7) << 4)),
                     dst + row*128 + kb);
        }
    };

    f32x4 acc[2][2][4][2];
    #pragma unroll
    for (int mr = 0; mr < 2; ++mr)
        #pragma unroll
        for (int nc = 0; nc < 2; ++nc)
            #pragma unroll
            for (int m = 0; m < 4; ++m)
                #pragma unroll
                for (int n = 0; n < 2; ++n)
                    acc[mr][nc][m][n] = (f32x4){0.f,0.f,0.f,0.f};

    bf16x8 a[4][2], b0[2][2], b1[2][2];
    const char* A0l = (const char*)As[0];
    const char* A1l = (const char*)As[1];
    const char* B0l = (const char*)Bs[0];
    const char* B1l = (const char*)Bs[1];

#define QLDA(AL, MR) { \
    _Pragma("unroll") for (int m_ = 0; m_ < 4; ++m_) { \
        _Pragma("unroll") for (int kk_ = 0; kk_ < 2; ++kk_) { \
            int row_ = wm*128 + (MR)*64 + m_*16 + fr; \
            a[m_][kk_] = *(const bf16x8*)((AL) + row_*128 + ((kk_*64 + g*16) ^ ((row_ & 7) << 4))); \
        } } }
#define QLDB(BL, NC, BB_) { \
    _Pragma("unroll") for (int n_ = 0; n_ < 2; ++n_) { \
        _Pragma("unroll") for (int kk_ = 0; kk_ < 2; ++kk_) { \
            int row_ = wn*64 + (NC)*32 + n_*16 + fr; \
            BB_[n_][kk_] = *(const bf16x8*)((BL) + row_*128 + ((kk_*64 + g*16) ^ ((row_ & 7) << 4))); \
        } } }
#define QMM(MR, NC, BB_) { \
    __builtin_amdgcn_s_setprio(1); \
    _Pragma("unroll") for (int m_ = 0; m_ < 4; ++m_) { \
        _Pragma("unroll") for (int n_ = 0; n_ < 2; ++n_) { \
            _Pragma("unroll") for (int kk_ = 0; kk_ < 2; ++kk_) { \
                acc[MR][NC][m_][n_] = __builtin_amdgcn_mfma_f32_16x16x32_bf16( \
                    a[m_][kk_], BB_[n_][kk_], acc[MR][NC][m_][n_], 0, 0, 0); \
        } } } \
    __builtin_amdgcn_s_setprio(0); }

    // prologue: t0 {A0,B0,B1,A1}, t1 {A0,B0,B1}; t1.A1 staged at i0.ph1
    stageA(0, 0, 0); stageB(0, 0, 0); stageB(1, 0, 0); stageA(1, 0, 0);
    stageA(0, 1, 1); stageB(0, 1, 1); stageB(1, 1, 1);
    VM0;
    rbar();

    const int NI = CC/128;              // 16 iterations, 2 K-tiles each
    #pragma unroll 1
    for (int i = 0; i < NI; ++i) {
        const int t1 = 2*i + 1, t2 = 2*i + 2, t3 = 2*i + 3;
        // ---- K-tile 2i from buf0 ----
        // ph1 (mr0,nc0): reads A0,B0
        VMW; QLDA(A0l, 0); QLDB(B0l, 0, b0); stageA(1, t1, 1);
        rbar(); QMM(0, 0, b0); rbar();
        // ph2 (mr0,nc1): reads B1 (a reused)
        VMW; QLDB(B0l, 1, b1); stageA(0, t2, 0);
        rbar(); QMM(0, 1, b1); rbar();
        // ph3 (mr1,nc0): reads A1 (b0 reused)
        VMW; QLDA(A0l, 1); stageB(0, t2, 0);
        rbar(); QMM(1, 0, b0); rbar();
        // ph4 (mr1,nc1): pure MFMA (a, b1 reused)
        VMW; stageB(1, t2, 0);
        rbar(); QMM(1, 1, b1); rbar();
        // ---- K-tile 2i+1 from buf1 ----
        // ph5
        VMW; QLDA(A1l, 0); QLDB(B1l, 0, b0); stageA(1, t2, 0);
        rbar(); QMM(0, 0, b0); rbar();
        // ph6
        VMW; QLDB(B1l, 1, b1); stageA(0, t3, 1);
        rbar(); QMM(0, 1, b1); rbar();
        // ph7
        VMW; QLDA(A1l, 1); stageB(0, t3, 1);
        rbar(); QMM(1, 0, b0); rbar();
        // ph8
        VMW; stageB(1, t3, 1);
        rbar(); QMM(1, 1, b1); rbar();
    }
#undef QLDA
#undef QLDB
#undef QMM

    // ---- epilogue: route n-tile (block-uniform section) -> Q / K / Vt ----
    const int sec = n0 >> 11;                      // 0..2 (sections 2048-aligned)
    const float scl = (sec == 0) ? qscale : 1.0f;
    const float* bp = (sec == 0) ? bq : ((sec == 1) ? bk : bv);
    #pragma unroll
    for (int mr = 0; mr < 2; ++mr)
        #pragma unroll
        for (int nc = 0; nc < 2; ++nc)
            #pragma unroll
            for (int n = 0; n < 2; ++n) {
                int nn = (n0 & 2047) + wn*64 + nc*32 + n*16 + fr;
                float bval = bp[nn];
                int h = nn >> 7, d = nn & (HS-1);
                #pragma unroll
                for (int m = 0; m < 4; ++m)
                    #pragma unroll
                    for (int r = 0; r < 4; ++r) {
                        int mg = m0 + wm*128 + mr*64 + m*16 + g*4 + r;
                        int bb2 = mg >> 11, tq = mg & (TT-1);
                        short ov = f2bf((acc[mr][nc][m][n][r] + bval) * scl);
                        if (sec == 0)      Qd [((size_t)(bb2*HH + h)*TT + tq)*HS + d] = ov;
                        else if (sec == 1) Kd [((size_t)(bb2*HH + h)*TT + tq)*HS + d] = ov;
                        else               Vtd[((size_t)(bb2*HH + h)*HS + d)*TT + tq] = ov;
                    }
            }
}

// ---------------- out-proj GEMM (proven 128^2 structure), fp32 out ----------------
__launch_bounds__(256)
__global__ void gemm_out_kernel(const short* __restrict__ A, const short* __restrict__ Bt,
                                const float* __restrict__ bias, float* __restrict__ dst)
{
    __shared__ __align__(16) short As[128*64];
    __shared__ __align__(16) short Bs[128*64];
    const int tid = threadIdx.x;
    const int lane = tid & 63;
    const int g = lane >> 4, fr = lane & 15;
    const int wid = tid >> 6;
    const int wr = wid >> 1, wc = wid & 1;

    const int bid = blockIdx.x;                   // 0..511
    const int m0 = (bid & 31) * 128;              // 32 m-tiles (fastest)
    const int n0 = (bid >> 5) * 128;              // 16 n-tiles

    f32x4 acc[4][4];
    #pragma unroll
    for (int i = 0; i < 4; ++i)
        #pragma unroll
        for (int j = 0; j < 4; ++j) acc[i][j] = (f32x4){0.f,0.f,0.f,0.f};

    for (int k0 = 0; k0 < CC; k0 += 64) {
        __syncthreads();
        #pragma unroll
        for (int i = 0; i < 4; ++i) {
            int c = i*256 + tid;
            int row = c >> 3;
            int kbl = ((c & 7) * 16) ^ ((row & 7) << 4);
            gl_lds16(reinterpret_cast<const char*>(A) + ((size_t)(m0+row)*CC + k0)*2 + kbl,
                     reinterpret_cast<char*>(As) + c*16);
        }
        #pragma unroll
        for (int i = 0; i < 4; ++i) {
            int c = i*256 + tid;
            int row = c >> 3;
            int kbl = ((c & 7) * 16) ^ ((row & 7) << 4);
            gl_lds16(reinterpret_cast<const char*>(Bt) + ((size_t)(n0+row)*CC + k0)*2 + kbl,
                     reinterpret_cast<char*>(Bs) + c*16);
        }
        __syncthreads();
        #pragma unroll
        for (int cch = 0; cch < 2; ++cch) {
            bf16x8 a[4], b[4];
            #pragma unroll
            for (int i = 0; i < 4; ++i) {
                int row = wr*64 + i*16 + fr;
                int kph = (cch*64 + g*16) ^ ((row & 7) << 4);
                a[i] = *reinterpret_cast<const bf16x8*>(
                    reinterpret_cast<const char*>(As) + row*128 + kph);
            }
            #pragma unroll
            for (int j = 0; j < 4; ++j) {
                int row = wc*64 + j*16 + fr;
                int kph = (cch*64 + g*16) ^ ((row & 7) << 4);
                b[j] = *reinterpret_cast<const bf16x8*>(
                    reinterpret_cast<const char*>(Bs) + row*128 + kph);
            }
            #pragma unroll
            for (int i = 0; i < 4; ++i)
                #pragma unroll
                for (int j = 0; j < 4; ++j)
                    acc[i][j] = __builtin_amdgcn_mfma_f32_16x16x32_bf16(a[i], b[j], acc[i][j], 0, 0, 0);
        }
    }

    #pragma unroll
    for (int j = 0; j < 4; ++j) {
        int n = n0 + wc*64 + j*16 + fr;
        float bval = bias[n];
        #pragma unroll
        for (int i = 0; i < 4; ++i)
            #pragma unroll
            for (int r = 0; r < 4; ++r) {
                int m = m0 + wr*64 + i*16 + g*4 + r;
                dst[(size_t)m*CC + n] = acc[i][j][r] + bval;
            }
    }
}

// ---------------- causal flash attention v5 + setprio (unchanged) ----------------
__launch_bounds__(256, 2)
__global__ void attn_kernel(const short* __restrict__ Q, const short* __restrict__ K,
                            const short* __restrict__ Vt, short* __restrict__ O)
{
    __shared__ __align__(16) short Ks[2][64*128];   // 2 x 16KB
    __shared__ __align__(16) short Vs[2][128*64];   // 2 x 16KB

    const int tid = threadIdx.x;
    const int lane = tid & 63;
    const int wid = tid >> 6;
    const int l5 = lane >> 5;
    const int q31 = lane & 31;
    const bool hif = (l5 != 0);

    const int dd = blockIdx.x;              // 0..511
    const int g8 = dd & 7;
    const int s  = (dd >> 3) & 31;
    const int half = dd >> 8;
    const int bh = g8*4 + (s >> 3);
    const int u  = s & 7;
    const int qb = half ? u : (15 - u);
    const int q0 = qb * 128;
    const int wq0 = q0 + wid*32;

    const short* Qh = Q + (size_t)bh * TT * HS;
    const char*  Kg = (const char*)(K  + (size_t)bh * TT * HS);
    const char*  Vg = (const char*)(Vt + (size_t)bh * HS * TT);

    bf16x8 qf[8];
    #pragma unroll
    for (int dk = 0; dk < 8; ++dk)
        qf[dk] = *reinterpret_cast<const bf16x8*>(
            Qh + (size_t)(wq0 + q31)*HS + dk*16 + l5*8);

    f32x16 o[4];
    #pragma unroll
    for (int c = 0; c < 4; ++c)
        #pragma unroll
        for (int r = 0; r < 16; ++r) o[c][r] = 0.f;
    float mrun = -1e30f, lrun = 0.f;

    auto stage = [&](int kv0, int p) {
        char* Kd = reinterpret_cast<char*>(Ks[p]);
        char* Vd = reinterpret_cast<char*>(Vs[p]);
        #pragma unroll
        for (int i = 0; i < 4; ++i) {
            int c = i*256 + tid;
            int row = c >> 4;
            int lg  = ((c & 15) * 16) ^ ((row & 7) << 4);
            gl_lds16(Kg + (size_t)(kv0 + row)*256 + lg, Kd + c*16);
        }
        #pragma unroll
        for (int i = 0; i < 4; ++i) {
            int c = i*256 + tid;
            int row = c >> 3;
            int lg  = ((c & 7) * 16) ^ ((row & 7) << 4);
            gl_lds16(Vg + ((size_t)row*TT + kv0)*2 + lg, Vd + c*16);
        }
    };

    const int nst = q0/64 + 2;
    stage(0, 0);

    for (int t = 0; t < nst; ++t) {
        const int kv0 = t * 64;
        __syncthreads();
        if (t + 1 < nst) stage(kv0 + 64, (t+1) & 1);

        if (kv0 > wq0 + 31) continue;

        const char* Kl = reinterpret_cast<const char*>(Ks[t & 1]);
        const char* Vl = reinterpret_cast<const char*>(Vs[t & 1]);

        f32x16 st[2];
        #pragma unroll
        for (int t2 = 0; t2 < 2; ++t2)
            #pragma unroll
            for (int r = 0; r < 16; ++r) st[t2][r] = 0.f;
        __builtin_amdgcn_s_setprio(1);
        #pragma unroll
        for (int t2 = 0; t2 < 2; ++t2) {
            int krow = t2*32 + q31;
            int rsw = (krow & 7) << 4;
            #pragma unroll
            for (int dk = 0; dk < 8; ++dk) {
                bf16x8 kf = *reinterpret_cast<const bf16x8*>(
                    Kl + krow*256 + ((dk*32 + l5*16) ^ rsw));
                st[t2] = __builtin_amdgcn_mfma_f32_32x32x16_bf16(kf, qf[dk], st[t2], 0, 0, 0);
            }
        }
        __builtin_amdgcn_s_setprio(0);
        if (kv0 + 63 > wq0) {
            int qrow = wq0 + q31;
            #pragma unroll
            for (int t2 = 0; t2 < 2; ++t2)
                #pragma unroll
                for (int r = 0; r < 16; ++r) {
                    int kv = kv0 + t2*32 + (r & 3) + ((r >> 2) << 3) + l5*4;
                    if (kv > qrow) st[t2][r] = -1e30f;
                }
        }
        float pm = -1e30f;
        #pragma unroll
        for (int t2 = 0; t2 < 2; ++t2)
            #pragma unroll
            for (int r = 0; r < 16; ++r) pm = fmaxf(pm, st[t2][r]);
        if (__any(pm > mrun + 8.f)) {
            float pmf = fmaxf(pm, __shfl_xor(pm, 32));
            float mn = fmaxf(mrun, pmf);
            float al = __builtin_amdgcn_exp2f(mrun - mn);
            mrun = mn; lrun *= al;
            #pragma unroll
            for (int c = 0; c < 4; ++c)
                #pragma unroll
                for (int r = 0; r < 16; ++r) o[c][r] *= al;
        }
        float ps = 0.f;
        #pragma unroll
        for (int t2 = 0; t2 < 2; ++t2)
            #pragma unroll
            for (int r = 0; r < 16; ++r) {
                float pv = __builtin_amdgcn_exp2f(st[t2][r] - mrun);
                st[t2][r] = pv;
                ps += pv;
            }
        lrun += ps;
        unsigned pw[2][8];
        #pragma unroll
        for (int t2 = 0; t2 < 2; ++t2)
            #pragma unroll
            for (int w = 0; w < 8; ++w)
                asm("v_cvt_pk_bf16_f32 %0, %1, %2"
                    : "=v"(pw[t2][w]) : "v"(st[t2][2*w]), "v"(st[t2][2*w+1]));
        #pragma unroll
        for (int c4 = 0; c4 < 4; ++c4) {
            int t2 = c4 >> 1, b0 = (c4 & 1) * 4;
            unsigned A0 = pw[t2][b0+0], A1 = pw[t2][b0+1];
            unsigned A2 = pw[t2][b0+2], A3 = pw[t2][b0+3];
            unsigned X0 = (unsigned)__shfl_xor((int)A0, 32);
            unsigned X1 = (unsigned)__shfl_xor((int)A1, 32);
            unsigned X2 = (unsigned)__shfl_xor((int)A2, 32);
            unsigned X3 = (unsigned)__shfl_xor((int)A3, 32);
            union { unsigned u[4]; bf16x8 v; } fu;
            fu.u[0] = hif ? X2 : A0;
            fu.u[1] = hif ? X3 : A1;
            fu.u[2] = hif ? A2 : X0;
            fu.u[3] = hif ? A3 : X1;
            __builtin_amdgcn_s_setprio(1);
            #pragma unroll
            for (int c = 0; c < 4; ++c) {
                int vrow = c*32 + q31;
                bf16x8 vf = *reinterpret_cast<const bf16x8*>(
                    Vl + vrow*128 + ((c4*32 + l5*16) ^ ((vrow & 7) << 4)));
                o[c] = __builtin_amdgcn_mfma_f32_32x32x16_bf16(vf, fu.v, o[c], 0, 0, 0);
            }
            __builtin_amdgcn_s_setprio(0);
        }
    }

    lrun += __shfl_xor(lrun, 32);
    float inv = 1.f / lrun;
    int b = bh >> 4, h = bh & 15;
    size_t base = ((size_t)(b*TT + wq0 + q31))*CC + (size_t)h*HS;
    #pragma unroll
    for (int c = 0; c < 4; ++c)
        #pragma unroll
        for (int g2 = 0; g2 < 4; ++g2) {
            bf16x4 v4;
            #pragma unroll
            for (int j = 0; j < 4; ++j) v4[j] = f2bf(o[c][g2*4 + j] * inv);
            *reinterpret_cast<bf16x4*>(O + base + c*32 + g2*8 + l5*4) = v4;
        }
}

extern "C" void kernel_launch(void* const* d_in, const int* in_sizes, int n_in,
                              void* d_out, int out_size, void* d_ws, size_t ws_size,
                              hipStream_t stream)
{
    const float* idx = (const float*)d_in[0];
    const float* Wq  = (const float*)d_in[1];
    const float* bq  = (const float*)d_in[2];
    const float* Wk  = (const float*)d_in[3];
    const float* bk  = (const float*)d_in[4];
    const float* Wv  = (const float*)d_in[5];
    const float* bv  = (const float*)d_in[6];
    const float* Wo  = (const float*)d_in[7];
    const float* bo  = (const float*)d_in[8];
    float* out = (float*)d_out;

    short* Xbf  = (short*)d_ws;
    short* Wcat = Xbf  + (size_t)MM*CC;          // [6144][2048] = Wq^T | Wk^T | Wv^T
    short* Wto  = Wcat + (size_t)3*CC*CC;
    short* Qb   = Wto  + (size_t)CC*CC;
    short* Kb   = Qb   + (size_t)MM*CC;
    short* Vtb  = Kb   + (size_t)MM*CC;
    short* Ob   = Vtb  + (size_t)MM*CC;

    cvt_bf16_kernel<<<1024, 256, 0, stream>>>(idx, Xbf, MM*CC);
    wt_kernel<<<dim3(CC/32, CC/32, 4), dim3(32, 8), 0, stream>>>(
        Wq, Wk, Wv, Wo,
        Wcat, Wcat + (size_t)CC*CC, Wcat + (size_t)2*CC*CC, Wto);

    const float qs = 0.08838834764831845f * 1.4426950408889634f;  // log2(e)/sqrt(128)
    gemm_qkv8_kernel<<<dim3(384), 512, 0, stream>>>(Xbf, Wcat, bq, bk, bv, Qb, Kb, Vtb, qs);

    attn_kernel<<<dim3(512), 256, 0, stream>>>(Qb, Kb, Vtb, Ob);

    gemm_out_kernel<<<dim3(512), 256, 0, stream>>>(Ob, Wto, bo, out);
}

// Round 12
// 283.285 us; speedup vs baseline: 1.0117x; 1.0095x over previous
//
#include <hip/hip_runtime.h>
#include <hip/hip_bf16.h>

#define TT 2048
#define CC 2048
#define HH 16
#define HS 128
#define BB 2
#define MM (BB*TT)   // 4096

typedef __attribute__((ext_vector_type(8))) short bf16x8;
typedef __attribute__((ext_vector_type(4))) short bf16x4;
typedef __attribute__((ext_vector_type(4))) float f32x4;
typedef __attribute__((ext_vector_type(16))) float f32x16;

__device__ __forceinline__ short f2bf(float x) {
    unsigned u = __float_as_uint(x);
    unsigned r = (u + 0x7FFFu + ((u >> 16) & 1u)) >> 16;
    return (short)r;
}

// direct global -> LDS async copy, 16B per lane (dest wave-uniform base + lane*16)
__device__ __forceinline__ void gl_lds16(const void* g, void* l) {
    __builtin_amdgcn_global_load_lds(
        (const __attribute__((address_space(1))) unsigned int*)g,
        (__attribute__((address_space(3))) unsigned int*)l,
        16, 0, 0);
}

// ---------------- fp32 -> bf16 convert (idx) ----------------
__global__ void cvt_bf16_kernel(const float* __restrict__ x, short* __restrict__ y, int n) {
    int stride = gridDim.x * blockDim.x;
    for (int i = blockIdx.x * blockDim.x + threadIdx.x; i < n/4; i += stride) {
        float4 v = reinterpret_cast<const float4*>(x)[i];
        bf16x4 s;
        s[0] = f2bf(v.x); s[1] = f2bf(v.y); s[2] = f2bf(v.z); s[3] = f2bf(v.w);
        reinterpret_cast<bf16x4*>(y)[i] = s;
    }
}

// ---------------- W [k][n] fp32  ->  Wt [n][k] bf16 ----------------
__global__ void wt_kernel(const float* __restrict__ w0, const float* __restrict__ w1,
                          const float* __restrict__ w2, const float* __restrict__ w3,
                          short* __restrict__ o0, short* __restrict__ o1,
                          short* __restrict__ o2, short* __restrict__ o3)
{
    const float* W; short* Wt;
    switch (blockIdx.z) {
        case 0:  W = w0; Wt = o0; break;
        case 1:  W = w1; Wt = o1; break;
        case 2:  W = w2; Wt = o2; break;
        default: W = w3; Wt = o3; break;
    }
    __shared__ float tile[32][33];
    int tx = threadIdx.x, ty = threadIdx.y;           // block (32,8)
    int k0 = blockIdx.x * 32, n0 = blockIdx.y * 32;
    #pragma unroll
    for (int i = 0; i < 4; ++i)
        tile[ty + i*8][tx] = W[(size_t)(k0 + ty + i*8) * CC + n0 + tx];
    __syncthreads();
    #pragma unroll
    for (int i = 0; i < 4; ++i)
        Wt[(size_t)(n0 + ty + i*8) * CC + k0 + tx] = f2bf(tile[tx][ty + i*8]);
}

// ---------------- GEMM (proven round-5 128^2 structure): C = A * Bt^T (+bias, *scale) ----------------
// MODE 0: dst = bf16 [B,H,T,hs] (Q/K);  MODE 1: dst = fp32 [M][N];  MODE 2: dst = bf16 [B,H,hs,T] (Vt)
template<int MODE>
__launch_bounds__(256)
__global__ void gemm_bt_kernel(const short* __restrict__ A, const short* __restrict__ Bt,
                               const float* __restrict__ bias, void* __restrict__ dst,
                               float scale)
{
    __shared__ __align__(16) short As[128*64];
    __shared__ __align__(16) short Bs[128*64];
    const int tid = threadIdx.x;
    const int lane = tid & 63;
    const int g = lane >> 4, fr = lane & 15;
    const int wid = tid >> 6;
    const int wr = wid >> 1, wc = wid & 1;
    const int m0 = blockIdx.x * 128, n0 = blockIdx.y * 128;

    f32x4 acc[4][4];
    #pragma unroll
    for (int i = 0; i < 4; ++i)
        #pragma unroll
        for (int j = 0; j < 4; ++j) acc[i][j] = (f32x4){0.f,0.f,0.f,0.f};

    for (int k0 = 0; k0 < CC; k0 += 64) {
        __syncthreads();
        #pragma unroll
        for (int i = 0; i < 4; ++i) {
            int c = i*256 + tid;
            int row = c >> 3;
            int kbl = ((c & 7) * 16) ^ ((row & 7) << 4);
            gl_lds16(reinterpret_cast<const char*>(A) + ((size_t)(m0+row)*CC + k0)*2 + kbl,
                     reinterpret_cast<char*>(As) + c*16);
        }
        #pragma unroll
        for (int i = 0; i < 4; ++i) {
            int c = i*256 + tid;
            int row = c >> 3;
            int kbl = ((c & 7) * 16) ^ ((row & 7) << 4);
            gl_lds16(reinterpret_cast<const char*>(Bt) + ((size_t)(n0+row)*CC + k0)*2 + kbl,
                     reinterpret_cast<char*>(Bs) + c*16);
        }
        __syncthreads();
        #pragma unroll
        for (int cch = 0; cch < 2; ++cch) {
            bf16x8 a[4], b[4];
            #pragma unroll
            for (int i = 0; i < 4; ++i) {
                int row = wr*64 + i*16 + fr;
                int kph = (cch*64 + g*16) ^ ((row & 7) << 4);
                a[i] = *reinterpret_cast<const bf16x8*>(
                    reinterpret_cast<const char*>(As) + row*128 + kph);
            }
            #pragma unroll
            for (int j = 0; j < 4; ++j) {
                int row = wc*64 + j*16 + fr;
                int kph = (cch*64 + g*16) ^ ((row & 7) << 4);
                b[j] = *reinterpret_cast<const bf16x8*>(
                    reinterpret_cast<const char*>(Bs) + row*128 + kph);
            }
            #pragma unroll
            for (int i = 0; i < 4; ++i)
                #pragma unroll
                for (int j = 0; j < 4; ++j)
                    acc[i][j] = __builtin_amdgcn_mfma_f32_16x16x32_bf16(a[i], b[j], acc[i][j], 0, 0, 0);
        }
    }

    #pragma unroll
    for (int j = 0; j < 4; ++j) {
        int n = n0 + wc*64 + j*16 + fr;
        float bv = bias[n];
        #pragma unroll
        for (int i = 0; i < 4; ++i) {
            #pragma unroll
            for (int r = 0; r < 4; ++r) {
                int m = m0 + wr*64 + i*16 + g*4 + r;
                float val = (acc[i][j][r] + bv) * scale;
                if (MODE == 0) {
                    int bb = m >> 11, t = m & (TT-1);
                    int h  = n >> 7,  d = n & (HS-1);
                    reinterpret_cast<short*>(dst)[((size_t)(bb*HH + h)*TT + t)*HS + d] = f2bf(val);
                } else if (MODE == 2) {
                    int bb = m >> 11, t = m & (TT-1);
                    int h  = n >> 7,  d = n & (HS-1);
                    reinterpret_cast<short*>(dst)[((size_t)(bb*HH + h)*HS + d)*TT + t] = f2bf(val);
                } else {
                    reinterpret_cast<float*>(dst)[(size_t)m*CC + n] = val;
                }
            }
        }
    }
}

// ---------------- causal flash attention v6: uniform-work blocks ----------------
// 512 blocks x 128 threads (2 waves x 32 q-rows). Each block: head bh, 64-row q-tile pair
// (31-p, p) processed SEQUENTIALLY -> exactly 33 kv-steps per block (no load imbalance,
// no tail; 2 blocks/CU co-resident, 2 independent barrier domains per CU throughout).
// K/V double-buffered in LDS via global_load_lds; one __syncthreads per step.
__launch_bounds__(128, 1)
__global__ void attn_kernel(const short* __restrict__ Q, const short* __restrict__ K,
                            const short* __restrict__ Vt, short* __restrict__ O)
{
    __shared__ __align__(16) short Ks[2][64*128];   // 2 x 16KB
    __shared__ __align__(16) short Vs[2][128*64];   // 2 x 16KB

    const int tid = threadIdx.x;        // 0..127
    const int lane = tid & 63;
    const int wid = tid >> 6;           // 0..1
    const int l5 = lane >> 5;
    const int q31 = lane & 31;
    const bool hif = (l5 != 0);

    const int dd = blockIdx.x;          // 0..511
    const int g8 = dd & 7;
    const int i0 = dd >> 3;             // 0..63
    const int bh = g8*4 + (i0 >> 4);    // 4 heads per XCD-group (KV L2-resident)
    const int p  = i0 & 15;             // pair id: tiles (31-p, p)
    const int nstA = 32 - p;            // steps for heavy tile (31-p)
    const int ntot = 33;                // nstA + (p+1), constant

    const short* Qh = Q + (size_t)bh * TT * HS;
    const char*  Kg = (const char*)(K  + (size_t)bh * TT * HS);
    const char*  Vg = (const char*)(Vt + (size_t)bh * HS * TT);

    int wq0 = (31 - p)*64 + wid*32;     // this wave's 32 q rows (seg A)

    bf16x8 qf[8];
    #pragma unroll
    for (int dk = 0; dk < 8; ++dk)
        qf[dk] = *reinterpret_cast<const bf16x8*>(
            Qh + (size_t)(wq0 + q31)*HS + dk*16 + l5*8);

    f32x16 o[4];
    #pragma unroll
    for (int c = 0; c < 4; ++c)
        #pragma unroll
        for (int r = 0; r < 16; ++r) o[c][r] = 0.f;
    float mrun = -1e30f, lrun = 0.f;

    auto stage = [&](int kv0, int pb) {
        char* Kd = reinterpret_cast<char*>(Ks[pb]);
        char* Vd = reinterpret_cast<char*>(Vs[pb]);
        #pragma unroll
        for (int i = 0; i < 8; ++i) {               // K tile: 64 rows x 256B
            int c = i*128 + tid;
            int row = c >> 4;
            int lg  = ((c & 15) * 16) ^ ((row & 7) << 4);
            gl_lds16(Kg + (size_t)(kv0 + row)*256 + lg, Kd + c*16);
        }
        #pragma unroll
        for (int i = 0; i < 8; ++i) {               // Vt tile: 128 rows x 128B
            int c = i*128 + tid;
            int row = c >> 3;
            int lg  = ((c & 7) * 16) ^ ((row & 7) << 4);
            gl_lds16(Vg + ((size_t)row*TT + kv0)*2 + lg, Vd + c*16);
        }
    };

    auto flush = [&]() {
        float lr = lrun + __shfl_xor(lrun, 32);
        float inv = 1.f / lr;
        int b = bh >> 4, h = bh & 15;
        size_t base = ((size_t)(b*TT + wq0 + q31))*CC + (size_t)h*HS;
        #pragma unroll
        for (int c = 0; c < 4; ++c)
            #pragma unroll
            for (int g2 = 0; g2 < 4; ++g2) {
                bf16x4 v4;
                #pragma unroll
                for (int j = 0; j < 4; ++j) v4[j] = f2bf(o[c][g2*4 + j] * inv);
                *reinterpret_cast<bf16x4*>(O + base + c*32 + g2*8 + l5*4) = v4;
            }
    };

    stage(0, 0);

    #pragma unroll 1
    for (int t = 0; t < ntot; ++t) {
        const int kv0 = ((t >= nstA) ? t - nstA : t) * 64;
        __syncthreads();                     // tile t ready (stage(t) drained)
        if (t + 1 < ntot) {
            int tn = t + 1;
            int kvn = ((tn >= nstA) ? tn - nstA : tn) * 64;
            stage(kvn, tn & 1);              // flies during compute of step t
        }
        if (t == nstA) {                     // seg boundary: store tile A, reset for tile B
            flush();
            wq0 = p*64 + wid*32;
            #pragma unroll
            for (int dk = 0; dk < 8; ++dk)
                qf[dk] = *reinterpret_cast<const bf16x8*>(
                    Qh + (size_t)(wq0 + q31)*HS + dk*16 + l5*8);
            #pragma unroll
            for (int c = 0; c < 4; ++c)
                #pragma unroll
                for (int r = 0; r < 16; ++r) o[c][r] = 0.f;
            mrun = -1e30f; lrun = 0.f;
        }

        const char* Kl = reinterpret_cast<const char*>(Ks[t & 1]);
        const char* Vl = reinterpret_cast<const char*>(Vs[t & 1]);

        // ---- S^T = K Q^T (swapped operands; lane owns q-row q31) ----
        f32x16 st[2];
        #pragma unroll
        for (int t2 = 0; t2 < 2; ++t2)
            #pragma unroll
            for (int r = 0; r < 16; ++r) st[t2][r] = 0.f;
        __builtin_amdgcn_s_setprio(1);
        #pragma unroll
        for (int t2 = 0; t2 < 2; ++t2) {
            int krow = t2*32 + q31;
            int rsw = (krow & 7) << 4;
            #pragma unroll
            for (int dk = 0; dk < 8; ++dk) {
                bf16x8 kf = *reinterpret_cast<const bf16x8*>(
                    Kl + krow*256 + ((dk*32 + l5*16) ^ rsw));
                st[t2] = __builtin_amdgcn_mfma_f32_32x32x16_bf16(kf, qf[dk], st[t2], 0, 0, 0);
            }
        }
        __builtin_amdgcn_s_setprio(0);
        // causal mask (near-diagonal steps only)
        if (kv0 + 63 > wq0) {
            int qrow = wq0 + q31;
            #pragma unroll
            for (int t2 = 0; t2 < 2; ++t2)
                #pragma unroll
                for (int r = 0; r < 16; ++r) {
                    int kv = kv0 + t2*32 + (r & 3) + ((r >> 2) << 3) + l5*4;
                    if (kv > qrow) st[t2][r] = -1e30f;
                }
        }
        // ---- online softmax (defer-max, exp2 domain, lane-owned row) ----
        float pm = -1e30f;
        #pragma unroll
        for (int t2 = 0; t2 < 2; ++t2)
            #pragma unroll
            for (int r = 0; r < 16; ++r) pm = fmaxf(pm, st[t2][r]);
        if (__any(pm > mrun + 8.f)) {
            float pmf = fmaxf(pm, __shfl_xor(pm, 32));
            float mn = fmaxf(mrun, pmf);
            float al = __builtin_amdgcn_exp2f(mrun - mn);
            mrun = mn; lrun *= al;
            #pragma unroll
            for (int c = 0; c < 4; ++c)
                #pragma unroll
                for (int r = 0; r < 16; ++r) o[c][r] *= al;
        }
        float ps = 0.f;
        #pragma unroll
        for (int t2 = 0; t2 < 2; ++t2)
            #pragma unroll
            for (int r = 0; r < 16; ++r) {
                float pv = __builtin_amdgcn_exp2f(st[t2][r] - mrun);
                st[t2][r] = pv;
                ps += pv;
            }
        lrun += ps;
        // ---- pack P to bf16 in-register ----
        unsigned pw[2][8];
        #pragma unroll
        for (int t2 = 0; t2 < 2; ++t2)
            #pragma unroll
            for (int w = 0; w < 8; ++w)
                asm("v_cvt_pk_bf16_f32 %0, %1, %2"
                    : "=v"(pw[t2][w]) : "v"(st[t2][2*w]), "v"(st[t2][2*w+1]));
        // ---- O += V^T P ----
        #pragma unroll
        for (int c4 = 0; c4 < 4; ++c4) {
            int t2 = c4 >> 1, b0 = (c4 & 1) * 4;
            unsigned A0 = pw[t2][b0+0], A1 = pw[t2][b0+1];
            unsigned A2 = pw[t2][b0+2], A3 = pw[t2][b0+3];
            unsigned X0 = (unsigned)__shfl_xor((int)A0, 32);
            unsigned X1 = (unsigned)__shfl_xor((int)A1, 32);
            unsigned X2 = (unsigned)__shfl_xor((int)A2, 32);
            unsigned X3 = (unsigned)__shfl_xor((int)A3, 32);
            union { unsigned u[4]; bf16x8 v; } fu;
            fu.u[0] = hif ? X2 : A0;
            fu.u[1] = hif ? X3 : A1;
            fu.u[2] = hif ? A2 : X0;
            fu.u[3] = hif ? A3 : X1;
            __builtin_amdgcn_s_setprio(1);
            #pragma unroll
            for (int c = 0; c < 4; ++c) {
                int vrow = c*32 + q31;
                bf16x8 vf = *reinterpret_cast<const bf16x8*>(
                    Vl + vrow*128 + ((c4*32 + l5*16) ^ ((vrow & 7) << 4)));
                o[c] = __builtin_amdgcn_mfma_f32_32x32x16_bf16(vf, fu.v, o[c], 0, 0, 0);
            }
            __builtin_amdgcn_s_setprio(0);
        }
    }

    flush();
}

extern "C" void kernel_launch(void* const* d_in, const int* in_sizes, int n_in,
                              void* d_out, int out_size, void* d_ws, size_t ws_size,
                              hipStream_t stream)
{
    const float* idx = (const float*)d_in[0];
    const float* Wq  = (const float*)d_in[1];
    const float* bq  = (const float*)d_in[2];
    const float* Wk  = (const float*)d_in[3];
    const float* bk  = (const float*)d_in[4];
    const float* Wv  = (const float*)d_in[5];
    const float* bv  = (const float*)d_in[6];
    const float* Wo  = (const float*)d_in[7];
    const float* bo  = (const float*)d_in[8];
    float* out = (float*)d_out;

    short* Xbf = (short*)d_ws;
    short* Wtq = Xbf + (size_t)MM*CC;
    short* Wtk = Wtq + (size_t)CC*CC;
    short* Wtv = Wtk + (size_t)CC*CC;
    short* Wto = Wtv + (size_t)CC*CC;
    short* Qb  = Wto + (size_t)CC*CC;
    short* Kb  = Qb  + (size_t)MM*CC;
    short* Vtb = Kb  + (size_t)MM*CC;
    short* Ob  = Vtb + (size_t)MM*CC;

    cvt_bf16_kernel<<<1024, 256, 0, stream>>>(idx, Xbf, MM*CC);
    wt_kernel<<<dim3(CC/32, CC/32, 4), dim3(32, 8), 0, stream>>>(
        Wq, Wk, Wv, Wo, Wtq, Wtk, Wtv, Wto);

    const float qs = 0.08838834764831845f * 1.4426950408889634f;  // log2(e)/sqrt(128)
    gemm_bt_kernel<0><<<dim3(MM/128, CC/128), 256, 0, stream>>>(Xbf, Wtq, bq, Qb, qs);
    gemm_bt_kernel<0><<<dim3(MM/128, CC/128), 256, 0, stream>>>(Xbf, Wtk, bk, Kb, 1.0f);
    gemm_bt_kernel<2><<<dim3(MM/128, CC/128), 256, 0, stream>>>(Xbf, Wtv, bv, Vtb, 1.0f);

    attn_kernel<<<dim3(512), 128, 0, stream>>>(Qb, Kb, Vtb, Ob);

    gemm_bt_kernel<1><<<dim3(MM/128, CC/128), 256, 0, stream>>>(Ob, Wto, bo, out, 1.0f);
}

// Round 13
// 268.648 us; speedup vs baseline: 1.0668x; 1.0545x over previous
//
#include <hip/hip_runtime.h>
#include <hip/hip_bf16.h>

#define TT 2048
#define CC 2048
#define HH 16
#define HS 128
#define BB 2
#define MM (BB*TT)   // 4096

typedef __attribute__((ext_vector_type(8))) short bf16x8;
typedef __attribute__((ext_vector_type(4))) short bf16x4;
typedef __attribute__((ext_vector_type(4))) float f32x4;
typedef __attribute__((ext_vector_type(16))) float f32x16;

__device__ __forceinline__ short f2bf(float x) {
    unsigned u = __float_as_uint(x);
    unsigned r = (u + 0x7FFFu + ((u >> 16) & 1u)) >> 16;
    return (short)r;
}

// direct global -> LDS async copy, 16B per lane (dest wave-uniform base + lane*16)
__device__ __forceinline__ void gl_lds16(const void* g, void* l) {
    __builtin_amdgcn_global_load_lds(
        (const __attribute__((address_space(1))) unsigned int*)g,
        (__attribute__((address_space(3))) unsigned int*)l,
        16, 0, 0);
}

// ---------------- fp32 -> bf16 convert (idx) ----------------
__global__ void cvt_bf16_kernel(const float* __restrict__ x, short* __restrict__ y, int n) {
    int stride = gridDim.x * blockDim.x;
    for (int i = blockIdx.x * blockDim.x + threadIdx.x; i < n/4; i += stride) {
        float4 v = reinterpret_cast<const float4*>(x)[i];
        bf16x4 s;
        s[0] = f2bf(v.x); s[1] = f2bf(v.y); s[2] = f2bf(v.z); s[3] = f2bf(v.w);
        reinterpret_cast<bf16x4*>(y)[i] = s;
    }
}

// ---------------- W [k][n] fp32  ->  Wt [n][k] bf16 ----------------
__global__ void wt_kernel(const float* __restrict__ w0, const float* __restrict__ w1,
                          const float* __restrict__ w2, const float* __restrict__ w3,
                          short* __restrict__ o0, short* __restrict__ o1,
                          short* __restrict__ o2, short* __restrict__ o3)
{
    const float* W; short* Wt;
    switch (blockIdx.z) {
        case 0:  W = w0; Wt = o0; break;
        case 1:  W = w1; Wt = o1; break;
        case 2:  W = w2; Wt = o2; break;
        default: W = w3; Wt = o3; break;
    }
    __shared__ float tile[32][33];
    int tx = threadIdx.x, ty = threadIdx.y;           // block (32,8)
    int k0 = blockIdx.x * 32, n0 = blockIdx.y * 32;
    #pragma unroll
    for (int i = 0; i < 4; ++i)
        tile[ty + i*8][tx] = W[(size_t)(k0 + ty + i*8) * CC + n0 + tx];
    __syncthreads();
    #pragma unroll
    for (int i = 0; i < 4; ++i)
        Wt[(size_t)(n0 + ty + i*8) * CC + k0 + tx] = f2bf(tile[tx][ty + i*8]);
}

// ---------------- GEMM (proven round-5 128^2 structure): C = A * Bt^T (+bias, *scale) ----------------
// MODE 0: dst = bf16 [B,H,T,hs] (Q/K);  MODE 1: dst = fp32 [M][N];  MODE 2: dst = bf16 [B,H,hs,T] (Vt)
template<int MODE>
__launch_bounds__(256)
__global__ void gemm_bt_kernel(const short* __restrict__ A, const short* __restrict__ Bt,
                               const float* __restrict__ bias, void* __restrict__ dst,
                               float scale)
{
    __shared__ __align__(16) short As[128*64];
    __shared__ __align__(16) short Bs[128*64];
    const int tid = threadIdx.x;
    const int lane = tid & 63;
    const int g = lane >> 4, fr = lane & 15;
    const int wid = tid >> 6;
    const int wr = wid >> 1, wc = wid & 1;
    const int m0 = blockIdx.x * 128, n0 = blockIdx.y * 128;

    f32x4 acc[4][4];
    #pragma unroll
    for (int i = 0; i < 4; ++i)
        #pragma unroll
        for (int j = 0; j < 4; ++j) acc[i][j] = (f32x4){0.f,0.f,0.f,0.f};

    for (int k0 = 0; k0 < CC; k0 += 64) {
        __syncthreads();
        #pragma unroll
        for (int i = 0; i < 4; ++i) {
            int c = i*256 + tid;
            int row = c >> 3;
            int kbl = ((c & 7) * 16) ^ ((row & 7) << 4);
            gl_lds16(reinterpret_cast<const char*>(A) + ((size_t)(m0+row)*CC + k0)*2 + kbl,
                     reinterpret_cast<char*>(As) + c*16);
        }
        #pragma unroll
        for (int i = 0; i < 4; ++i) {
            int c = i*256 + tid;
            int row = c >> 3;
            int kbl = ((c & 7) * 16) ^ ((row & 7) << 4);
            gl_lds16(reinterpret_cast<const char*>(Bt) + ((size_t)(n0+row)*CC + k0)*2 + kbl,
                     reinterpret_cast<char*>(Bs) + c*16);
        }
        __syncthreads();
        #pragma unroll
        for (int cch = 0; cch < 2; ++cch) {
            bf16x8 a[4], b[4];
            #pragma unroll
            for (int i = 0; i < 4; ++i) {
                int row = wr*64 + i*16 + fr;
                int kph = (cch*64 + g*16) ^ ((row & 7) << 4);
                a[i] = *reinterpret_cast<const bf16x8*>(
                    reinterpret_cast<const char*>(As) + row*128 + kph);
            }
            #pragma unroll
            for (int j = 0; j < 4; ++j) {
                int row = wc*64 + j*16 + fr;
                int kph = (cch*64 + g*16) ^ ((row & 7) << 4);
                b[j] = *reinterpret_cast<const bf16x8*>(
                    reinterpret_cast<const char*>(Bs) + row*128 + kph);
            }
            #pragma unroll
            for (int i = 0; i < 4; ++i)
                #pragma unroll
                for (int j = 0; j < 4; ++j)
                    acc[i][j] = __builtin_amdgcn_mfma_f32_16x16x32_bf16(a[i], b[j], acc[i][j], 0, 0, 0);
        }
    }

    #pragma unroll
    for (int j = 0; j < 4; ++j) {
        int n = n0 + wc*64 + j*16 + fr;
        float bv = bias[n];
        #pragma unroll
        for (int i = 0; i < 4; ++i) {
            #pragma unroll
            for (int r = 0; r < 4; ++r) {
                int m = m0 + wr*64 + i*16 + g*4 + r;
                float val = (acc[i][j][r] + bv) * scale;
                if (MODE == 0) {
                    int bb = m >> 11, t = m & (TT-1);
                    int h  = n >> 7,  d = n & (HS-1);
                    reinterpret_cast<short*>(dst)[((size_t)(bb*HH + h)*TT + t)*HS + d] = f2bf(val);
                } else if (MODE == 2) {
                    int bb = m >> 11, t = m & (TT-1);
                    int h  = n >> 7,  d = n & (HS-1);
                    reinterpret_cast<short*>(dst)[((size_t)(bb*HH + h)*HS + d)*TT + t] = f2bf(val);
                } else {
                    reinterpret_cast<float*>(dst)[(size_t)m*CC + n] = val;
                }
            }
        }
    }
}

// ---------------- causal flash attention v5 + LPT dispatch order ----------------
// 512 blocks x 256 threads (4 waves x 32 q-rows), kv-step 64.
// LPT mapping: qb = 15-(dd>>5) -> all heaviest blocks (32 steps) dispatch first across
// the 256 CUs; light blocks backfill freed slots (classic makespan heuristic).
// K/V double-buffered in LDS via global_load_lds; one __syncthreads per step.
__launch_bounds__(256, 2)
__global__ void attn_kernel(const short* __restrict__ Q, const short* __restrict__ K,
                            const short* __restrict__ Vt, short* __restrict__ O)
{
    __shared__ __align__(16) short Ks[2][64*128];   // 2 x 16KB
    __shared__ __align__(16) short Vs[2][128*64];   // 2 x 16KB

    const int tid = threadIdx.x;
    const int lane = tid & 63;
    const int wid = tid >> 6;
    const int l5 = lane >> 5;
    const int q31 = lane & 31;
    const bool hif = (l5 != 0);

    const int dd = blockIdx.x;              // 0..511
    const int qb = 15 - (dd >> 5);          // LPT: heavy q-tiles first
    const int bh = dd & 31;                 // head 0..31
    const int q0 = qb * 128;
    const int wq0 = q0 + wid*32;

    const short* Qh = Q + (size_t)bh * TT * HS;
    const char*  Kg = (const char*)(K  + (size_t)bh * TT * HS);
    const char*  Vg = (const char*)(Vt + (size_t)bh * HS * TT);

    bf16x8 qf[8];
    #pragma unroll
    for (int dk = 0; dk < 8; ++dk)
        qf[dk] = *reinterpret_cast<const bf16x8*>(
            Qh + (size_t)(wq0 + q31)*HS + dk*16 + l5*8);

    f32x16 o[4];
    #pragma unroll
    for (int c = 0; c < 4; ++c)
        #pragma unroll
        for (int r = 0; r < 16; ++r) o[c][r] = 0.f;
    float mrun = -1e30f, lrun = 0.f;

    auto stage = [&](int kv0, int p) {
        char* Kd = reinterpret_cast<char*>(Ks[p]);
        char* Vd = reinterpret_cast<char*>(Vs[p]);
        #pragma unroll
        for (int i = 0; i < 4; ++i) {
            int c = i*256 + tid;
            int row = c >> 4;
            int lg  = ((c & 15) * 16) ^ ((row & 7) << 4);
            gl_lds16(Kg + (size_t)(kv0 + row)*256 + lg, Kd + c*16);
        }
        #pragma unroll
        for (int i = 0; i < 4; ++i) {
            int c = i*256 + tid;
            int row = c >> 3;
            int lg  = ((c & 7) * 16) ^ ((row & 7) << 4);
            gl_lds16(Vg + ((size_t)row*TT + kv0)*2 + lg, Vd + c*16);
        }
    };

    const int nst = q0/64 + 2;
    stage(0, 0);

    for (int t = 0; t < nst; ++t) {
        const int kv0 = t * 64;
        __syncthreads();
        if (t + 1 < nst) stage(kv0 + 64, (t+1) & 1);

        if (kv0 > wq0 + 31) continue;

        const char* Kl = reinterpret_cast<const char*>(Ks[t & 1]);
        const char* Vl = reinterpret_cast<const char*>(Vs[t & 1]);

        // ---- S^T = K Q^T (swapped operands; lane owns q-row q31) ----
        f32x16 st[2];
        #pragma unroll
        for (int t2 = 0; t2 < 2; ++t2)
            #pragma unroll
            for (int r = 0; r < 16; ++r) st[t2][r] = 0.f;
        __builtin_amdgcn_s_setprio(1);
        #pragma unroll
        for (int t2 = 0; t2 < 2; ++t2) {
            int krow = t2*32 + q31;
            int rsw = (krow & 7) << 4;
            #pragma unroll
            for (int dk = 0; dk < 8; ++dk) {
                bf16x8 kf = *reinterpret_cast<const bf16x8*>(
                    Kl + krow*256 + ((dk*32 + l5*16) ^ rsw));
                st[t2] = __builtin_amdgcn_mfma_f32_32x32x16_bf16(kf, qf[dk], st[t2], 0, 0, 0);
            }
        }
        __builtin_amdgcn_s_setprio(0);
        if (kv0 + 63 > wq0) {
            int qrow = wq0 + q31;
            #pragma unroll
            for (int t2 = 0; t2 < 2; ++t2)
                #pragma unroll
                for (int r = 0; r < 16; ++r) {
                    int kv = kv0 + t2*32 + (r & 3) + ((r >> 2) << 3) + l5*4;
                    if (kv > qrow) st[t2][r] = -1e30f;
                }
        }
        // ---- online softmax (defer-max, exp2 domain, lane-owned row) ----
        float pm = -1e30f;
        #pragma unroll
        for (int t2 = 0; t2 < 2; ++t2)
            #pragma unroll
            for (int r = 0; r < 16; ++r) pm = fmaxf(pm, st[t2][r]);
        if (__any(pm > mrun + 8.f)) {
            float pmf = fmaxf(pm, __shfl_xor(pm, 32));
            float mn = fmaxf(mrun, pmf);
            float al = __builtin_amdgcn_exp2f(mrun - mn);
            mrun = mn; lrun *= al;
            #pragma unroll
            for (int c = 0; c < 4; ++c)
                #pragma unroll
                for (int r = 0; r < 16; ++r) o[c][r] *= al;
        }
        float ps = 0.f;
        #pragma unroll
        for (int t2 = 0; t2 < 2; ++t2)
            #pragma unroll
            for (int r = 0; r < 16; ++r) {
                float pv = __builtin_amdgcn_exp2f(st[t2][r] - mrun);
                st[t2][r] = pv;
                ps += pv;
            }
        lrun += ps;
        // ---- pack P to bf16 in-register ----
        unsigned pw[2][8];
        #pragma unroll
        for (int t2 = 0; t2 < 2; ++t2)
            #pragma unroll
            for (int w = 0; w < 8; ++w)
                asm("v_cvt_pk_bf16_f32 %0, %1, %2"
                    : "=v"(pw[t2][w]) : "v"(st[t2][2*w]), "v"(st[t2][2*w+1]));
        // ---- O += V^T P ----
        #pragma unroll
        for (int c4 = 0; c4 < 4; ++c4) {
            int t2 = c4 >> 1, b0 = (c4 & 1) * 4;
            unsigned A0 = pw[t2][b0+0], A1 = pw[t2][b0+1];
            unsigned A2 = pw[t2][b0+2], A3 = pw[t2][b0+3];
            unsigned X0 = (unsigned)__shfl_xor((int)A0, 32);
            unsigned X1 = (unsigned)__shfl_xor((int)A1, 32);
            unsigned X2 = (unsigned)__shfl_xor((int)A2, 32);
            unsigned X3 = (unsigned)__shfl_xor((int)A3, 32);
            union { unsigned u[4]; bf16x8 v; } fu;
            fu.u[0] = hif ? X2 : A0;
            fu.u[1] = hif ? X3 : A1;
            fu.u[2] = hif ? A2 : X0;
            fu.u[3] = hif ? A3 : X1;
            __builtin_amdgcn_s_setprio(1);
            #pragma unroll
            for (int c = 0; c < 4; ++c) {
                int vrow = c*32 + q31;
                bf16x8 vf = *reinterpret_cast<const bf16x8*>(
                    Vl + vrow*128 + ((c4*32 + l5*16) ^ ((vrow & 7) << 4)));
                o[c] = __builtin_amdgcn_mfma_f32_32x32x16_bf16(vf, fu.v, o[c], 0, 0, 0);
            }
            __builtin_amdgcn_s_setprio(0);
        }
    }

    lrun += __shfl_xor(lrun, 32);
    float inv = 1.f / lrun;
    int b = bh >> 4, h = bh & 15;
    size_t base = ((size_t)(b*TT + wq0 + q31))*CC + (size_t)h*HS;
    #pragma unroll
    for (int c = 0; c < 4; ++c)
        #pragma unroll
        for (int g2 = 0; g2 < 4; ++g2) {
            bf16x4 v4;
            #pragma unroll
            for (int j = 0; j < 4; ++j) v4[j] = f2bf(o[c][g2*4 + j] * inv);
            *reinterpret_cast<bf16x4*>(O + base + c*32 + g2*8 + l5*4) = v4;
        }
}

extern "C" void kernel_launch(void* const* d_in, const int* in_sizes, int n_in,
                              void* d_out, int out_size, void* d_ws, size_t ws_size,
                              hipStream_t stream)
{
    const float* idx = (const float*)d_in[0];
    const float* Wq  = (const float*)d_in[1];
    const float* bq  = (const float*)d_in[2];
    const float* Wk  = (const float*)d_in[3];
    const float* bk  = (const float*)d_in[4];
    const float* Wv  = (const float*)d_in[5];
    const float* bv  = (const float*)d_in[6];
    const float* Wo  = (const float*)d_in[7];
    const float* bo  = (const float*)d_in[8];
    float* out = (float*)d_out;

    short* Xbf = (short*)d_ws;
    short* Wtq = Xbf + (size_t)MM*CC;
    short* Wtk = Wtq + (size_t)CC*CC;
    short* Wtv = Wtk + (size_t)CC*CC;
    short* Wto = Wtv + (size_t)CC*CC;
    short* Qb  = Wto + (size_t)CC*CC;
    short* Kb  = Qb  + (size_t)MM*CC;
    short* Vtb = Kb  + (size_t)MM*CC;
    short* Ob  = Vtb + (size_t)MM*CC;

    cvt_bf16_kernel<<<1024, 256, 0, stream>>>(idx, Xbf, MM*CC);
    wt_kernel<<<dim3(CC/32, CC/32, 4), dim3(32, 8), 0, stream>>>(
        Wq, Wk, Wv, Wo, Wtq, Wtk, Wtv, Wto);

    const float qs = 0.08838834764831845f * 1.4426950408889634f;  // log2(e)/sqrt(128)
    gemm_bt_kernel<0><<<dim3(MM/128, CC/128), 256, 0, stream>>>(Xbf, Wtq, bq, Qb, qs);
    gemm_bt_kernel<0><<<dim3(MM/128, CC/128), 256, 0, stream>>>(Xbf, Wtk, bk, Kb, 1.0f);
    gemm_bt_kernel<2><<<dim3(MM/128, CC/128), 256, 0, stream>>>(Xbf, Wtv, bv, Vtb, 1.0f);

    attn_kernel<<<dim3(512), 256, 0, stream>>>(Qb, Kb, Vtb, Ob);

    gemm_bt_kernel<1><<<dim3(MM/128, CC/128), 256, 0, stream>>>(Ob, Wto, bo, out, 1.0f);
}